// Round 5
// baseline (505.464 us; speedup 1.0000x reference)
//
#include <hip/hip_runtime.h>
#include <hip/hip_bf16.h>
#include <stdint.h>

#define NUM_EMB 4096
#define EMB_DIM 256
#define NVEC 65536                     // 64*32*32
#define OUT0_SIZE (NVEC * EMB_DIM)     // z_q_ste elements; loss scalar follows
#define MTILE 128                      // z rows per block
#define DCONST 0.0625f                 // positivity shift for packed distance
#define LROW 528                       // bytes per z-row in LDS (512 + 16)

typedef __bf16 bf16x8 __attribute__((ext_vector_type(8)));
typedef float floatx4 __attribute__((ext_vector_type(4)));

static __device__ __forceinline__ unsigned int f2bf(float f) {
  unsigned int u = __float_as_uint(f);
  return (u + 0x7fffu + ((u >> 16) & 1u)) >> 16;  // RNE fp32->bf16
}

// Prep: codebook fp32 -> bf16 (ws), -(||e||^2 + DCONST)/2 (ws), zero loss slot.
__global__ void __launch_bounds__(256) vq_prep(const float* __restrict__ cbf,
                                               unsigned short* __restrict__ cbb,
                                               float* __restrict__ nhe,
                                               float* __restrict__ out) {
  int w = threadIdx.x >> 6;
  int lane = threadIdx.x & 63;
  int row = blockIdx.x * 4 + w;
  float4 v = ((const float4*)(cbf + (size_t)row * EMB_DIM))[lane];
  float ss = v.x * v.x + v.y * v.y + v.z * v.z + v.w * v.w;
  ushort4 b;
  b.x = (unsigned short)f2bf(v.x);
  b.y = (unsigned short)f2bf(v.y);
  b.z = (unsigned short)f2bf(v.z);
  b.w = (unsigned short)f2bf(v.w);
  ((ushort4*)(cbb + (size_t)row * EMB_DIM))[lane] = b;
#pragma unroll
  for (int m = 1; m < 64; m <<= 1) ss += __shfl_xor(ss, m, 64);
  if (lane == 0) nhe[row] = -0.5f * (ss + DCONST);
  if (blockIdx.x == 0 && threadIdx.x == 0) out[OUT0_SIZE] = 0.0f;
}

// Main: A (128 z rows) staged ONCE to LDS as bf16; barrier-free K-loop streams
// B global(L2)->regs (dbuf). ||e||^2 pre-folded into the MFMA acc init, so the
// epilogue per element is v_and_or + v_min. Packed (dist|idx) argmin.
__global__ void __launch_bounds__(256, 2) vq_main(const float* __restrict__ z,
                                                  const float* __restrict__ cbf,
                                                  const unsigned short* __restrict__ cbb,
                                                  const float* __restrict__ nhe,
                                                  float* __restrict__ out) {
  __shared__ unsigned char ldsA[MTILE * LROW];   // 67584 B
  __shared__ unsigned int minlds[4][MTILE];      // 2048 B
  __shared__ int idx_lds[MTILE];                 // 512 B
  __shared__ float wsum[8];

  const int t = threadIdx.x;
  const int w = t >> 6;
  const int lane = t & 63;
  const int q = lane >> 4;     // quad
  const int i = lane & 15;
  const int blk = blockIdx.x;

  // ---- Phase 1: stage z-tile (128x256 fp32 -> bf16) into LDS + block sumsq.
  // Thread t, iter j: float4 id = t + 256j -> row id>>6, col4 id&63. Coalesced.
  float s = 0.f;
  const float4* zp = (const float4*)(z + (size_t)blk * MTILE * EMB_DIM);
#pragma unroll 8
  for (int j = 0; j < 32; ++j) {
    int id = t + 256 * j;
    int r = id >> 6, c4 = id & 63;
    float4 v = zp[id];
    s += v.x * v.x + v.y * v.y + v.z * v.z + v.w * v.w;
    uint2 b;
    b.x = f2bf(v.x) | (f2bf(v.y) << 16);
    b.y = f2bf(v.z) | (f2bf(v.w) << 16);
    *(uint2*)(ldsA + r * LROW + c4 * 8) = b;
  }
#pragma unroll
  for (int m = 1; m < 64; m <<= 1) s += __shfl_xor(s, m, 64);
  if (lane == 0) wsum[w] = s;
  __syncthreads();

  // ---- Phase 2: K-loop. Wave w covers cols it*64 + w*16 + i.
  unsigned int pmin[32];
#pragma unroll
  for (int k = 0; k < 32; ++k) pmin[k] = 0xFFFFFFFFu;

  const unsigned short* bp = cbb + ((size_t)(w * 16 + i) * EMB_DIM + q * 8);
  const float* ep = nhe + w * 16 + i;

  uint4 bA[8], bB[8];
  float nhA, nhB;
#pragma unroll
  for (int ks = 0; ks < 8; ++ks) bA[ks] = *(const uint4*)(bp + ks * 32);
  nhA = ep[0];

#define VQ_COMPUTE(BUF, NH, IT)                                              \
  {                                                                          \
    floatx4 acc[8];                                                          \
    _Pragma("unroll") for (int g = 0; g < 8; ++g)                            \
        acc[g] = (floatx4){NH, NH, NH, NH};                                  \
    _Pragma("unroll") for (int g = 0; g < 8; ++g) {                          \
      const unsigned char* ap = ldsA + (g * 16 + i) * LROW + q * 16;         \
      _Pragma("unroll") for (int ks = 0; ks < 8; ++ks) {                     \
        bf16x8 a = __builtin_bit_cast(bf16x8, *(const uint4*)(ap + ks * 64));\
        acc[g] = __builtin_amdgcn_mfma_f32_16x16x32_bf16(                    \
            a, __builtin_bit_cast(bf16x8, BUF[ks]), acc[g], 0, 0, 0);        \
      }                                                                      \
    }                                                                        \
    unsigned int colb = (unsigned int)((IT) * 64 + w * 16 + i);              \
    _Pragma("unroll") for (int g = 0; g < 8; ++g)                            \
      _Pragma("unroll") for (int r = 0; r < 4; ++r) {                        \
        unsigned int p = (__float_as_uint(acc[g][r]) & 0x7FFFF000u) | colb;  \
        pmin[g * 4 + r] = min(pmin[g * 4 + r], p);                           \
      }                                                                      \
  }

  for (int it = 0; it < 64; it += 2) {
    {  // prefetch it+1
      const unsigned short* p1 = bp + (size_t)(it + 1) * 64 * EMB_DIM;
#pragma unroll
      for (int ks = 0; ks < 8; ++ks) bB[ks] = *(const uint4*)(p1 + ks * 32);
      nhB = ep[(it + 1) * 64];
    }
    VQ_COMPUTE(bA, nhA, it);
    {  // prefetch it+2 (wrap on last; result unused)
      int t2 = (it + 2 < 64) ? it + 2 : 0;
      const unsigned short* p2 = bp + (size_t)t2 * 64 * EMB_DIM;
#pragma unroll
      for (int ks = 0; ks < 8; ++ks) bA[ks] = *(const uint4*)(p2 + ks * 32);
      nhA = ep[t2 * 64];
    }
    VQ_COMPUTE(bB, nhB, it + 1);
  }

  // ---- Phase 3: reduce over the 16 col-lanes (xor 1..8 permutes i only).
  // Packed u32 min = (distance, index) lexicographic -> np.argmin tiebreak.
#pragma unroll
  for (int k = 0; k < 32; ++k) {
    unsigned int v = pmin[k];
#pragma unroll
    for (int m = 1; m <= 8; m <<= 1) v = min(v, __shfl_xor(v, m, 64));
    pmin[k] = v;
  }
  // C/D layout 16x16: col = lane&15, row = quad*4 + reg (+ g*16).
  if (i == 0) {
#pragma unroll
    for (int g = 0; g < 8; ++g)
#pragma unroll
      for (int r = 0; r < 4; ++r)
        minlds[w][g * 16 + q * 4 + r] = pmin[g * 4 + r];
  }
  __syncthreads();

  // Combine the 4 waves' col-quarters; stored value v = d/2 where
  // d = ||e||^2 + DCONST - 2*dot. Row loss = ||z||^2 + 2v - DCONST;
  // sum(||z||^2) over the tile came from phase 1.
  float rl = 0.f;
  if (t < MTILE) {
    unsigned int m = min(min(minlds[0][t], minlds[1][t]),
                         min(minlds[2][t], minlds[3][t]));
    idx_lds[t] = (int)(m & 0xFFFu);
    rl = 2.0f * __uint_as_float(m & 0x7FFFF000u) - DCONST;
  }
#pragma unroll
  for (int m = 1; m < 64; m <<= 1) rl += __shfl_xor(rl, m, 64);
  if (lane == 0) wsum[4 + w] = rl;
  __syncthreads();
  if (t == 0) {
    float tot = ((wsum[0] + wsum[1]) + (wsum[2] + wsum[3]))
              + ((wsum[4] + wsum[5]) + (wsum[6] + wsum[7]));
    atomicAdd(out + OUT0_SIZE, tot * (1.25f / (float)OUT0_SIZE));
  }

  // ---- Phase 4: gather codebook rows -> output (== z + (z_q - z) to ~3e-7).
#pragma unroll 4
  for (int j = 0; j < 32; ++j) {
    int id4 = j * 256 + t;     // float4 index within 128x256 tile
    int r = id4 >> 6, c4 = id4 & 63;
    int k = idx_lds[r];
    float4 ev = ((const float4*)(cbf + (size_t)k * EMB_DIM))[c4];
    ((float4*)(out + (size_t)(blk * MTILE + r) * EMB_DIM))[c4] = ev;
  }
}

extern "C" void kernel_launch(void* const* d_in, const int* in_sizes, int n_in,
                              void* d_out, int out_size, void* d_ws, size_t ws_size,
                              hipStream_t stream) {
  const float* z = (const float*)d_in[0];
  const float* cbf = (const float*)d_in[1];
  unsigned short* cbb = (unsigned short*)d_ws;                         // 2 MB bf16 codebook
  float* nhe = (float*)((char*)d_ws + (size_t)NUM_EMB * EMB_DIM * 2);  // +16 KB
  float* out = (float*)d_out;
  vq_prep<<<NUM_EMB / 4, 256, 0, stream>>>(cbf, cbb, nhe, out);
  vq_main<<<NVEC / MTILE, 256, 0, stream>>>(z, cbf, cbb, nhe, out);
}